// Round 9
// baseline (205.331 us; speedup 1.0000x reference)
//
#include <hip/hip_runtime.h>
#include <hip/hip_bf16.h>
#include <stdint.h>

#define N_PTS  100000
#define K_CL   256
#define F_DIM  256
#define NTILES 1563      // ceil(N_PTS/64)
#define GRID   512       // 2 blocks/CU

using bf16x8 = __attribute__((ext_vector_type(8))) short;
using f32x4  = __attribute__((ext_vector_type(4))) float;
typedef unsigned long long u64;

// 2x f32 -> packed 2x bf16 (RNE); compiler emits v_cvt_pk_bf16_f32
__device__ __forceinline__ unsigned pk2(float a, float b) {
    __hip_bfloat162 h = __float22bfloat162_rn(make_float2(a, b));
    unsigned u;
    __builtin_memcpy(&u, &h, 4);
    return u;
}

// ---------------- Kernel A: c -> fragment-contiguous bf16 hi/lo ----------
// frag index fi = ((k/16)*8 + it)*64 + kg*16 + (k%16), 16 B each
// (8 bf16 = feats it*32 + kg*8 .. +8 of cluster k). A wave-load of 64
// consecutive fragments = one coalesced 1 KB read = exact MFMA B operand.
__global__ void prep_kernel(const float* __restrict__ c,
                            unsigned short* __restrict__ chf,
                            unsigned short* __restrict__ clf,
                            float* __restrict__ csq,
                            u64* __restrict__ best) {
    const int k = blockIdx.x;      // one cluster per 64-thread block
    const int lane = threadIdx.x;
    float s = 0.f;
    if (lane < 32) {
        const int b = lane;                    // 8-feat block 0..31
        const float* src = c + (size_t)k * F_DIM + b * 8;
        float4 v0 = *(const float4*)(src);
        float4 v1 = *(const float4*)(src + 4);
        float e[8] = {v0.x, v0.y, v0.z, v0.w, v1.x, v1.y, v1.z, v1.w};
        unsigned h[4], l[4];
        #pragma unroll
        for (int j = 0; j < 4; ++j) {
            h[j] = pk2(e[2 * j], e[2 * j + 1]);
            float r0 = e[2 * j]     - __uint_as_float(h[j] << 16);
            float r1 = e[2 * j + 1] - __uint_as_float(h[j] & 0xFFFF0000u);
            l[j] = pk2(r0, r1);
            s = fmaf(e[2 * j], e[2 * j], s);
            s = fmaf(e[2 * j + 1], e[2 * j + 1], s);
        }
        const size_t fi = ((size_t)(k >> 4) * 8 + (b >> 2)) * 64
                        + (b & 3) * 16 + (k & 15);
        *(uint4*)(chf + fi * 8) = make_uint4(h[0], h[1], h[2], h[3]);
        *(uint4*)(clf + fi * 8) = make_uint4(l[0], l[1], l[2], l[3]);
    }
    #pragma unroll
    for (int off = 16; off; off >>= 1) s += __shfl_down(s, off, 64);
    if (lane == 0) { csq[k] = s; best[k] = 0xFFFFFFFFFFFFFFFFULL; }
}

// ---------------- Kernel B: persistent pipelined MFMA + argmin -----------
// 512 blocks x 256 thr (4 waves); block grid-strides over 64-pt tiles.
// Wave w: all 64 pts x clusters [64w, 64w+64) (cg=0..3), acc[4][4] f32x4.
// Pipeline per tile: compute t -> issue loads t+1 -> epilogue t -> barrier
// -> convert+write t+1 -> barrier. LDS swizzle p=(b+9r+2(r>>4))&31 is
// conflict-free for b64 writes and b128 frag reads (derivation in journal).
// D layout: col=lane&15 (cluster), row=(lane>>4)*4+reg (point) [m89/m91].
__global__ __launch_bounds__(256, 2)
void cluster_argmin_kernel(const float* __restrict__ x,
                           const unsigned short* __restrict__ chf,
                           const unsigned short* __restrict__ clf,
                           const float* __restrict__ csq,
                           u64* __restrict__ best) {
    __shared__ unsigned short xh_lds[64 * 256];   // 32 KB, swizzled
    __shared__ unsigned short xl_lds[64 * 256];   // 32 KB, swizzled
    __shared__ float xsq_lds[2][64];

    const int tid  = threadIdx.x;
    const int lane = tid & 63;
    const int w    = __builtin_amdgcn_readfirstlane(tid >> 6);
    const int r15  = lane & 15;      // MFMA row/col within 16-group
    const int kg   = lane >> 4;      // MFMA k-slice / staging row-subgroup
    const int m    = r15;            // staging col-lane
    const int rg   = kg;             // staging row-lane

    // c fragment base pointers: wave w covers groups 4w..4w+3
    const unsigned short* fh[4];
    const unsigned short* fl[4];
    float csq_r[4];
    #pragma unroll
    for (int cg = 0; cg < 4; ++cg) {
        size_t base = (size_t)(4 * w + cg) * 8 * 512 + lane * 8;
        fh[cg] = chf + base;
        fl[cg] = clf + base;
        csq_r[cg] = csq[w * 64 + cg * 16 + r15];
    }

    u64 keep = 0xFFFFFFFFFFFFFFFFULL;
    float4 v[16];

    // ---- staging helpers (fully unrolled; all v[] indices static) ----
    auto stage_issue = [&](int tile) {
        const int n0 = tile * 64;
        #pragma unroll
        for (int rs = 0; rs < 4; ++rs) {
            #pragma unroll
            for (int cs = 0; cs < 4; ++cs) {
                const int r = rs * 16 + w * 4 + rg;
                int gn = n0 + r;
                if (gn > N_PTS - 1) gn = N_PTS - 1;   // dup tail; masked later
                v[rs * 4 + cs] =
                    *(const float4*)(x + (size_t)gn * F_DIM + cs * 64 + m * 4);
            }
        }
    };
    auto stage_write = [&](int buf) {
        #pragma unroll
        for (int rs = 0; rs < 4; ++rs) {
            const int r = rs * 16 + w * 4 + rg;
            float s = 0.f;
            #pragma unroll
            for (int cs = 0; cs < 4; ++cs) {
                float4 e = v[rs * 4 + cs];
                unsigned h01 = pk2(e.x, e.y);
                unsigned h23 = pk2(e.z, e.w);
                float q0 = e.x - __uint_as_float(h01 << 16);
                float q1 = e.y - __uint_as_float(h01 & 0xFFFF0000u);
                float q2 = e.z - __uint_as_float(h23 << 16);
                float q3 = e.w - __uint_as_float(h23 & 0xFFFF0000u);
                unsigned l01 = pk2(q0, q1);
                unsigned l23 = pk2(q2, q3);
                const int b = cs * 8 + (m >> 1);
                const int p = (b + 9 * r + 2 * (r >> 4)) & 31;
                const int so = r * 256 + p * 8 + (m & 1) * 4;
                *(uint2*)&xh_lds[so] = make_uint2(h01, h23);
                *(uint2*)&xl_lds[so] = make_uint2(l01, l23);
                s = fmaf(e.x, e.x, s);
                s = fmaf(e.y, e.y, s);
                s = fmaf(e.z, e.z, s);
                s = fmaf(e.w, e.w, s);
            }
            s += __shfl_xor(s, 1, 64);
            s += __shfl_xor(s, 2, 64);
            s += __shfl_xor(s, 4, 64);
            s += __shfl_xor(s, 8, 64);
            if (m == 0) xsq_lds[buf][r] = s;
        }
    };

    // ---- prologue: stage first tile ----
    int tile = blockIdx.x;
    stage_issue(tile);
    stage_write(0);
    __syncthreads();
    int buf = 0;

    while (true) {
        const int nxt = tile + GRID;
        const bool have_nxt = (nxt < NTILES);
        const int n0 = tile * 64;

        // ---- compute: 8 feature-chunks, 48 MFMA each ----
        f32x4 acc[4][4];
        #pragma unroll
        for (int pg = 0; pg < 4; ++pg)
            #pragma unroll
            for (int cg = 0; cg < 4; ++cg)
                acc[pg][cg] = (f32x4){0.f, 0.f, 0.f, 0.f};

        #pragma unroll 2
        for (int it = 0; it < 8; ++it) {
            bf16x8 bh[4], bl[4];
            #pragma unroll
            for (int cg = 0; cg < 4; ++cg) {
                bh[cg] = *(const bf16x8*)(fh[cg] + it * 512);
                bl[cg] = *(const bf16x8*)(fl[cg] + it * 512);
            }
            bf16x8 xh8[4], xl8[4];
            #pragma unroll
            for (int pg = 0; pg < 4; ++pg) {
                const int r = pg * 16 + r15;
                const int p = (4 * it + kg + 9 * r + 2 * (r >> 4)) & 31;
                const int so = r * 256 + p * 8;
                xh8[pg] = *(const bf16x8*)&xh_lds[so];
                xl8[pg] = *(const bf16x8*)&xl_lds[so];
            }
            __builtin_amdgcn_s_setprio(1);
            #pragma unroll
            for (int pg = 0; pg < 4; ++pg) {
                #pragma unroll
                for (int cg = 0; cg < 4; ++cg) {
                    acc[pg][cg] = __builtin_amdgcn_mfma_f32_16x16x32_bf16(
                        xh8[pg], bh[cg], acc[pg][cg], 0, 0, 0);
                    acc[pg][cg] = __builtin_amdgcn_mfma_f32_16x16x32_bf16(
                        xh8[pg], bl[cg], acc[pg][cg], 0, 0, 0);
                    acc[pg][cg] = __builtin_amdgcn_mfma_f32_16x16x32_bf16(
                        xl8[pg], bh[cg], acc[pg][cg], 0, 0, 0);
                }
            }
            __builtin_amdgcn_s_setprio(0);
        }

        // issue next tile's loads: they fly under epilogue + barrier + the
        // co-resident block's compute; consumed only in stage_write.
        if (have_nxt) stage_issue(nxt);

        // ---- epilogue: pack (sqrt-dist bits << 32 | n), per-cluster min ----
        float4 xs[4];
        #pragma unroll
        for (int pg = 0; pg < 4; ++pg)
            xs[pg] = *(const float4*)&xsq_lds[buf][pg * 16 + kg * 4];
        #pragma unroll
        for (int cg = 0; cg < 4; ++cg) {
            const float cs = csq_r[cg];
            u64 mm = 0xFFFFFFFFFFFFFFFFULL;
            #pragma unroll
            for (int pg = 0; pg < 4; ++pg) {
                #pragma unroll
                for (int rr = 0; rr < 4; ++rr) {
                    const int n = n0 + pg * 16 + kg * 4 + rr;
                    float d2 = fmaf(-2.f, acc[pg][cg][rr], xs[pg][rr] + cs);
                    d2 = fmaxf(d2, 0.f);
                    float d = sqrtf(d2);
                    u64 pk = ((u64)__float_as_uint(d) << 32) | (unsigned)n;
                    if (n >= N_PTS) pk = 0xFFFFFFFFFFFFFFFFULL;
                    mm = pk < mm ? pk : mm;
                }
            }
            u64 o = __shfl_xor(mm, 16, 64); mm = o < mm ? o : mm;
            o = __shfl_xor(mm, 32, 64);     mm = o < mm ? o : mm;
            if (kg == cg) keep = keep < mm ? keep : mm;   // lane owns kb+lane
        }

        __syncthreads();
        if (have_nxt) stage_write(buf ^ 1);
        __syncthreads();
        if (!have_nxt) break;
        tile = nxt;
        buf ^= 1;
    }

    // one filtered atomic per lane per block (lane owns cluster w*64+lane)
    u64 cur = best[w * 64 + lane];
    if (keep < cur) atomicMin(&best[w * 64 + lane], keep);
}

// ---------------- Kernel C: gather winners ----------------
__global__ void gather_kernel(const float* __restrict__ x,
                              const u64* __restrict__ best,
                              float* __restrict__ out) {
    int k = blockIdx.x;
    unsigned int idx = (unsigned int)(best[k] & 0xFFFFFFFFULL);
    int t = threadIdx.x; // 64 threads, float4 each = 256 floats
    float4 v = *(const float4*)(x + (size_t)idx * F_DIM + t * 4);
    *(float4*)(out + (size_t)k * F_DIM + t * 4) = v;
}

extern "C" void kernel_launch(void* const* d_in, const int* in_sizes, int n_in,
                              void* d_out, int out_size, void* d_ws, size_t ws_size,
                              hipStream_t stream) {
    const float* x = (const float*)d_in[0];          // (1, N, F) f32
    const float* c = (const float*)d_in[1];          // (K, F)   f32
    float* out = (float*)d_out;                      // (1, K, F) f32

    u64* best  = (u64*)d_ws;                                         // 2 KB
    float* csq = (float*)((char*)d_ws + K_CL * sizeof(u64));         // 1 KB

    // fragment-ordered c hi/lo live in d_out (2 x 128 KB = exact fit);
    // the final gather overwrites d_out.
    unsigned short* chf = (unsigned short*)d_out;
    unsigned short* clf = chf + (size_t)K_CL * F_DIM;

    prep_kernel<<<K_CL, 64, 0, stream>>>(c, chf, clf, csq, best);

    cluster_argmin_kernel<<<GRID, 256, 0, stream>>>(x, chf, clf, csq, best);

    gather_kernel<<<K_CL, 64, 0, stream>>>(x, best, out);
}

// Round 10
// 199.343 us; speedup vs baseline: 1.0300x; 1.0300x over previous
//
#include <hip/hip_runtime.h>
#include <hip/hip_bf16.h>
#include <stdint.h>

#define N_PTS  100000
#define K_CL   256
#define F_DIM  256
#define NTILES 1563      // ceil(N_PTS/64)
#define GRID   256       // persistent, 1 block/CU

using bf16x8 = __attribute__((ext_vector_type(8))) short;
using f32x4  = __attribute__((ext_vector_type(4))) float;
typedef unsigned long long u64;

// 2x f32 -> packed 2x bf16 (RNE); compiler emits v_cvt_pk_bf16_f32
__device__ __forceinline__ unsigned pk2(float a, float b) {
    __hip_bfloat162 h = __float22bfloat162_rn(make_float2(a, b));
    unsigned u;
    __builtin_memcpy(&u, &h, 4);
    return u;
}

// ---------------- Kernel A: c -> fragment-contiguous bf16 hi/lo ----------
// frag index fi = ((k/16)*8 + it)*64 + kg*16 + (k%16), 16 B each
// (8 bf16 = feats it*32 + kg*8 .. +8 of cluster k). A wave-load of 64
// consecutive fragments = one coalesced 1 KB read = exact MFMA B operand.
__global__ void prep_kernel(const float* __restrict__ c,
                            unsigned short* __restrict__ chf,
                            unsigned short* __restrict__ clf,
                            float* __restrict__ csq,
                            u64* __restrict__ best) {
    const int k = blockIdx.x;      // one cluster per 64-thread block
    const int lane = threadIdx.x;
    float s = 0.f;
    if (lane < 32) {
        const int b = lane;                    // 8-feat block 0..31
        const float* src = c + (size_t)k * F_DIM + b * 8;
        float4 v0 = *(const float4*)(src);
        float4 v1 = *(const float4*)(src + 4);
        float e[8] = {v0.x, v0.y, v0.z, v0.w, v1.x, v1.y, v1.z, v1.w};
        unsigned h[4], l[4];
        #pragma unroll
        for (int j = 0; j < 4; ++j) {
            h[j] = pk2(e[2 * j], e[2 * j + 1]);
            float r0 = e[2 * j]     - __uint_as_float(h[j] << 16);
            float r1 = e[2 * j + 1] - __uint_as_float(h[j] & 0xFFFF0000u);
            l[j] = pk2(r0, r1);
            s = fmaf(e[2 * j], e[2 * j], s);
            s = fmaf(e[2 * j + 1], e[2 * j + 1], s);
        }
        const size_t fi = ((size_t)(k >> 4) * 8 + (b >> 2)) * 64
                        + (b & 3) * 16 + (k & 15);
        *(uint4*)(chf + fi * 8) = make_uint4(h[0], h[1], h[2], h[3]);
        *(uint4*)(clf + fi * 8) = make_uint4(l[0], l[1], l[2], l[3]);
    }
    #pragma unroll
    for (int off = 16; off; off >>= 1) s += __shfl_down(s, off, 64);
    if (lane == 0) { csq[k] = s; best[k] = 0xFFFFFFFFFFFFFFFFULL; }
}

// ---------------- Kernel B: persistent pipelined MFMA + argmin -----------
// 256 blocks (1/CU) x 512 thr (8 waves); block grid-strides over 64-pt
// tiles. Wave w: 64 pts x clusters [32w,32w+32) -> acc[4][2] f32x4 = 32 reg.
// Per tile: issue x-loads(t+1) -> compute(t) -> epilogue(t) -> barrier ->
// convert+write(t+1) -> barrier. c-frags manually double-buffered in named
// registers (A/B sets) so the compiler cannot JIT them (r8 lesson, VGPR=52).
// LDS XOR swizzle p = b ^ ((row&7)<<2): <=2-way (free) for b128 writes AND
// b128 frag reads (b bits: 0-2 or 0-1 vary per lane; XOR hits bits 2-4).
// D layout: col=lane&15 (cluster), row=(lane>>4)*4+reg (point) [m89/m91].
__global__ __launch_bounds__(512, 2)
void cluster_argmin_kernel(const float* __restrict__ x,
                           const unsigned short* __restrict__ chf,
                           const unsigned short* __restrict__ clf,
                           const float* __restrict__ csq,
                           u64* __restrict__ best) {
    __shared__ unsigned short xh_lds[64 * 256];   // 32 KB
    __shared__ unsigned short xl_lds[64 * 256];   // 32 KB
    __shared__ float xsq_lds[64];

    const int tid  = threadIdx.x;
    const int lane = tid & 63;
    const int w    = __builtin_amdgcn_readfirstlane(tid >> 6);
    const int r15  = lane & 15;
    const int kg   = lane >> 4;
    const int srow = tid >> 3;     // staging row 0..63
    const int sl   = tid & 7;      // staging lane-in-row

    // c fragment base pointers (wave w -> cluster groups 2w, 2w+1)
    const unsigned short* fh0 = chf + (size_t)(2 * w)     * 8 * 512 + lane * 8;
    const unsigned short* fh1 = chf + (size_t)(2 * w + 1) * 8 * 512 + lane * 8;
    const unsigned short* fl0 = clf + (size_t)(2 * w)     * 8 * 512 + lane * 8;
    const unsigned short* fl1 = clf + (size_t)(2 * w + 1) * 8 * 512 + lane * 8;
    const float csq0 = csq[w * 32 + r15];
    const float csq1 = csq[w * 32 + 16 + r15];

    u64 keep = 0xFFFFFFFFFFFFFFFFULL;
    float4 v[8];                   // 32 VGPR staging buffer (static idx only)

    auto load_v = [&](int t) {
        int gr = t * 64 + srow;
        if (gr > N_PTS - 1) gr = N_PTS - 1;        // dup tail; masked later
        const float* base = x + (size_t)gr * F_DIM + sl * 8;
        #pragma unroll
        for (int j = 0; j < 4; ++j) {
            v[2 * j]     = *(const float4*)(base + j * 64);
            v[2 * j + 1] = *(const float4*)(base + j * 64 + 4);
        }
    };
    auto write_stage = [&]() {
        float s = 0.f;
        #pragma unroll
        for (int j = 0; j < 4; ++j) {
            float4 a = v[2 * j], b = v[2 * j + 1];
            unsigned h0 = pk2(a.x, a.y), h1 = pk2(a.z, a.w);
            unsigned h2 = pk2(b.x, b.y), h3 = pk2(b.z, b.w);
            float q0 = a.x - __uint_as_float(h0 << 16);
            float q1 = a.y - __uint_as_float(h0 & 0xFFFF0000u);
            float q2 = a.z - __uint_as_float(h1 << 16);
            float q3 = a.w - __uint_as_float(h1 & 0xFFFF0000u);
            float q4 = b.x - __uint_as_float(h2 << 16);
            float q5 = b.y - __uint_as_float(h2 & 0xFFFF0000u);
            float q6 = b.z - __uint_as_float(h3 << 16);
            float q7 = b.w - __uint_as_float(h3 & 0xFFFF0000u);
            unsigned l0 = pk2(q0, q1), l1 = pk2(q2, q3);
            unsigned l2 = pk2(q4, q5), l3 = pk2(q6, q7);
            const int blk = sl + 8 * j;                  // logical 16B block
            const int p   = blk ^ ((srow & 7) << 2);     // phys (swizzled)
            const int so  = srow * 256 + p * 8;
            *(uint4*)&xh_lds[so] = make_uint4(h0, h1, h2, h3);
            *(uint4*)&xl_lds[so] = make_uint4(l0, l1, l2, l3);
            s = fmaf(a.x, a.x, s); s = fmaf(a.y, a.y, s);
            s = fmaf(a.z, a.z, s); s = fmaf(a.w, a.w, s);
            s = fmaf(b.x, b.x, s); s = fmaf(b.y, b.y, s);
            s = fmaf(b.z, b.z, s); s = fmaf(b.w, b.w, s);
        }
        s += __shfl_xor(s, 1, 64);
        s += __shfl_xor(s, 2, 64);
        s += __shfl_xor(s, 4, 64);
        if (sl == 0) xsq_lds[srow] = s;
    };

    // ---- prologue: stage first tile ----
    int tile = blockIdx.x;
    load_v(tile);
    write_stage();
    __syncthreads();

    while (true) {
        const int nxt = tile + GRID;
        const bool have = (nxt < NTILES);
        if (have) load_v(nxt);     // in flight under the whole compute phase

        f32x4 acc[4][2];
        #pragma unroll
        for (int pg = 0; pg < 4; ++pg) {
            acc[pg][0] = (f32x4){0.f, 0.f, 0.f, 0.f};
            acc[pg][1] = (f32x4){0.f, 0.f, 0.f, 0.f};
        }

        auto compute_it = [&](int it, bf16x8 bh0, bf16x8 bh1,
                              bf16x8 bl0, bf16x8 bl1) {
            bf16x8 xh8[4], xl8[4];
            const int p = ((it ^ (r15 & 7)) << 2) | kg;  // swizzled block
            #pragma unroll
            for (int pg = 0; pg < 4; ++pg) {
                const int so = (pg * 16 + r15) * 256 + p * 8;
                xh8[pg] = *(const bf16x8*)&xh_lds[so];
                xl8[pg] = *(const bf16x8*)&xl_lds[so];
            }
            __builtin_amdgcn_s_setprio(1);
            #pragma unroll
            for (int pg = 0; pg < 4; ++pg) {
                acc[pg][0] = __builtin_amdgcn_mfma_f32_16x16x32_bf16(
                    xh8[pg], bh0, acc[pg][0], 0, 0, 0);
                acc[pg][0] = __builtin_amdgcn_mfma_f32_16x16x32_bf16(
                    xh8[pg], bl0, acc[pg][0], 0, 0, 0);
                acc[pg][0] = __builtin_amdgcn_mfma_f32_16x16x32_bf16(
                    xl8[pg], bh0, acc[pg][0], 0, 0, 0);
                acc[pg][1] = __builtin_amdgcn_mfma_f32_16x16x32_bf16(
                    xh8[pg], bh1, acc[pg][1], 0, 0, 0);
                acc[pg][1] = __builtin_amdgcn_mfma_f32_16x16x32_bf16(
                    xh8[pg], bl1, acc[pg][1], 0, 0, 0);
                acc[pg][1] = __builtin_amdgcn_mfma_f32_16x16x32_bf16(
                    xl8[pg], bh1, acc[pg][1], 0, 0, 0);
            }
            __builtin_amdgcn_s_setprio(0);
        };

        // manual reg double-buffer of c-frags: B holds even it, A odd it
        bf16x8 bBh0 = *(const bf16x8*)(fh0), bBh1 = *(const bf16x8*)(fh1);
        bf16x8 bBl0 = *(const bf16x8*)(fl0), bBl1 = *(const bf16x8*)(fl1);
        #pragma unroll
        for (int ii = 0; ii < 4; ++ii) {
            const int itE = 2 * ii, itO = 2 * ii + 1;
            bf16x8 bAh0 = *(const bf16x8*)(fh0 + itO * 512);
            bf16x8 bAh1 = *(const bf16x8*)(fh1 + itO * 512);
            bf16x8 bAl0 = *(const bf16x8*)(fl0 + itO * 512);
            bf16x8 bAl1 = *(const bf16x8*)(fl1 + itO * 512);
            compute_it(itE, bBh0, bBh1, bBl0, bBl1);
            if (ii < 3) {
                bBh0 = *(const bf16x8*)(fh0 + (itE + 2) * 512);
                bBh1 = *(const bf16x8*)(fh1 + (itE + 2) * 512);
                bBl0 = *(const bf16x8*)(fl0 + (itE + 2) * 512);
                bBl1 = *(const bf16x8*)(fl1 + (itE + 2) * 512);
            }
            compute_it(itO, bAh0, bAh1, bAl0, bAl1);
        }

        // ---- epilogue: per-thread d2-argmin, one sqrt, u64 pack, 2 shfl ----
        const int n0t = tile * 64;
        float4 xs[4];
        #pragma unroll
        for (int pg = 0; pg < 4; ++pg)
            xs[pg] = *(const float4*)&xsq_lds[pg * 16 + kg * 4];
        #pragma unroll
        for (int cg = 0; cg < 2; ++cg) {
            const float cs = (cg == 0) ? csq0 : csq1;
            float bd2 = 3.4e38f;
            int bn = 0;
            #pragma unroll
            for (int pg = 0; pg < 4; ++pg) {
                #pragma unroll
                for (int rr = 0; rr < 4; ++rr) {
                    const int n = n0t + pg * 16 + kg * 4 + rr;   // increasing
                    float d2 = fmaf(-2.f, acc[pg][cg][rr], xs[pg][rr] + cs);
                    bool ok = (n < N_PTS) && (d2 < bd2);         // strict: first min
                    bd2 = ok ? d2 : bd2;
                    bn  = ok ? n  : bn;
                }
            }
            float d = sqrtf(fmaxf(bd2, 0.f));
            u64 pk = ((u64)__float_as_uint(d) << 32) | (unsigned)bn;
            u64 o = __shfl_xor(pk, 16, 64); pk = o < pk ? o : pk;
            o = __shfl_xor(pk, 32, 64);     pk = o < pk ? o : pk;
            if (kg == cg) keep = pk < keep ? pk : keep;   // lane<32 owns 32w+lane
        }

        __syncthreads();
        if (have) write_stage();
        __syncthreads();
        if (!have) break;
        tile = nxt;
    }

    // one filtered atomic per owned cluster
    if (lane < 32) {
        const int cl_ = w * 32 + lane;
        u64 cur = best[cl_];                 // stale is only ever >= true min
        if (keep < cur) atomicMin(&best[cl_], keep);
    }
}

// ---------------- Kernel C: gather winners ----------------
__global__ void gather_kernel(const float* __restrict__ x,
                              const u64* __restrict__ best,
                              float* __restrict__ out) {
    int k = blockIdx.x;
    unsigned int idx = (unsigned int)(best[k] & 0xFFFFFFFFULL);
    int t = threadIdx.x; // 64 threads, float4 each = 256 floats
    float4 v = *(const float4*)(x + (size_t)idx * F_DIM + t * 4);
    *(float4*)(out + (size_t)k * F_DIM + t * 4) = v;
}

extern "C" void kernel_launch(void* const* d_in, const int* in_sizes, int n_in,
                              void* d_out, int out_size, void* d_ws, size_t ws_size,
                              hipStream_t stream) {
    const float* x = (const float*)d_in[0];          // (1, N, F) f32
    const float* c = (const float*)d_in[1];          // (K, F)   f32
    float* out = (float*)d_out;                      // (1, K, F) f32

    u64* best  = (u64*)d_ws;                                         // 2 KB
    float* csq = (float*)((char*)d_ws + K_CL * sizeof(u64));         // 1 KB

    // fragment-ordered c hi/lo live in d_out (2 x 128 KB = exact fit);
    // the final gather overwrites d_out.
    unsigned short* chf = (unsigned short*)d_out;
    unsigned short* clf = chf + (size_t)K_CL * F_DIM;

    prep_kernel<<<K_CL, 64, 0, stream>>>(c, chf, clf, csq, best);

    cluster_argmin_kernel<<<GRID, 512, 0, stream>>>(x, chf, clf, csq, best);

    gather_kernel<<<K_CL, 64, 0, stream>>>(x, best, out);
}